// Round 6
// baseline (46.619 us; speedup 1.0000x reference)
//
#include <hip/hip_runtime.h>
#include <math.h>

#define L_TAPS 16
#define M_FFT  64
#define SMAX   128
#define BLOCK  320    // 5 waves: waves 0-4 stream (280/320 lanes), wave 4 also does H_t

typedef float v4f __attribute__((ext_vector_type(4)));

__global__ __launch_bounds__(BLOCK) void channel_fused(
    const float* __restrict__ xr, const float* __restrict__ xi,
    const float* __restrict__ cr, const float* __restrict__ ci,
    const int*   __restrict__ ns_ptr,
    float* __restrict__ out,          // [NP*SMK] real(out), then [NP*64] real(H_t)
    int NP, int SMK)
{
    __shared__ float2 s_w[SMAX];      // weights for this row, slot = s

    const int tid = threadIdx.x;
    const int np  = blockIdx.x;
    const int S   = ns_ptr[0] + 2;    // N_PILOT = 2
    const int MK  = SMK / S;
    const float two_pi = 6.2831853071795864f;

    const float* crow = cr + (size_t)np * L_TAPS;   // 64 B, L1-resident after first touch
    const float* cirow = ci + (size_t)np * L_TAPS;

    const int nvr = SMK >> 2;         // 280 in bench
    const bool fast = ((MK & 3) == 0) && ((SMK & 3) == 0) && (nvr <= BLOCK) && (S <= SMAX);

    if (fast) {
        const size_t gb = (size_t)np * nvr;
        const bool act = tid < nvr;
        v4f a, b;
        // 1) issue streaming loads FIRST — everything below hides under their latency
        if (act) {
            a = __builtin_nontemporal_load((const v4f*)xr + gb + tid);
            b = __builtin_nontemporal_load((const v4f*)xi + gb + tid);
        }
        // 2) H_t on wave 4: m = tid-256.  Re(H_t) = sum_l cr*cos(2pi*m*l/64) + ci*sin(...)
        if (tid >= BLOCK - 64) {
            const int m = tid - (BLOCK - 64);
            float hr = 0.f;
            #pragma unroll
            for (int l = 0; l < L_TAPS; ++l) {
                float sp, cp;
                __sincosf((float)((m * l) & (M_FFT - 1)) * (two_pi / (float)M_FFT), &sp, &cp);
                hr += crow[l] * cp + cirow[l] * sp;
            }
            __builtin_nontemporal_store(
                hr, out + (size_t)NP * SMK + (size_t)np * M_FFT + m);
        }
        // 3) weights on tid < S:  w_s = sum_l cof_l * exp(i*dop_l*t_s)
        if (tid < S) {
            const float t = (float)tid * (0.0005f / 14.0f);   // reference hard-codes /14
            float wr = 0.f, wi = 0.f;
            #pragma unroll
            for (int l = 0; l < L_TAPS; ++l) {
                float dop = two_pi * 1000.0f                  // fd = V/c*fc = 1000 Hz
                          * __cosf((float)l * (two_pi / (float)(L_TAPS - 1)));
                float sp, cp;
                __sincosf(dop * t, &sp, &cp);
                wr += crow[l] * cp - cirow[l] * sp;
                wi += crow[l] * sp + cirow[l] * cp;
            }
            s_w[tid] = make_float2(wr, wi);
        }
        __syncthreads();
        // 4) single uniform streaming shot
        if (act) {
            float2 w = s_w[(unsigned)tid / (unsigned)(MK >> 2)];
            __builtin_nontemporal_store(a * w.x - b * w.y, (v4f*)out + gb + tid);
        }
        return;
    }

    // ---------------- generic fallback (never hit in bench) ----------------
    // H_t
    if (tid >= BLOCK - 64) {
        const int m = tid - (BLOCK - 64);
        float hr = 0.f;
        #pragma unroll
        for (int l = 0; l < L_TAPS; ++l) {
            float sp, cp;
            __sincosf((float)((m * l) & (M_FFT - 1)) * (two_pi / (float)M_FFT), &sp, &cp);
            hr += crow[l] * cp + cirow[l] * sp;
        }
        out[(size_t)NP * SMK + (size_t)np * M_FFT + m] = hr;
    }
    if (S <= SMAX) {
        if (tid < S) {
            const float t = (float)tid * (0.0005f / 14.0f);
            float wr = 0.f, wi = 0.f;
            #pragma unroll
            for (int l = 0; l < L_TAPS; ++l) {
                float dop = two_pi * 1000.0f
                          * __cosf((float)l * (two_pi / (float)(L_TAPS - 1)));
                float sp, cp;
                __sincosf(dop * t, &sp, &cp);
                wr += crow[l] * cp - cirow[l] * sp;
                wi += crow[l] * sp + cirow[l] * cp;
            }
            s_w[tid] = make_float2(wr, wi);
        }
        __syncthreads();
        const size_t gb = (size_t)np * SMK;
        for (int i = tid; i < SMK; i += BLOCK) {
            float2 w = s_w[(unsigned)i / (unsigned)MK];
            out[gb + i] = xr[gb + i] * w.x - xi[gb + i] * w.y;
        }
    } else {
        const size_t gb = (size_t)np * SMK;
        for (int i = tid; i < SMK; i += BLOCK) {
            int s = i / MK;
            float t = (float)s * (0.0005f / 14.0f);
            float wr = 0.f, wi = 0.f;
            #pragma unroll
            for (int l = 0; l < L_TAPS; ++l) {
                float dop = two_pi * 1000.0f
                          * __cosf((float)l * (two_pi / (float)(L_TAPS - 1)));
                float sp, cp;
                __sincosf(dop * t, &sp, &cp);
                wr += crow[l] * cp - cirow[l] * sp;
                wi += crow[l] * sp + cirow[l] * cp;
            }
            out[gb + i] = xr[gb + i] * wr - xi[gb + i] * wi;
        }
    }
}

extern "C" void kernel_launch(void* const* d_in, const int* in_sizes, int n_in,
                              void* d_out, int out_size, void* d_ws, size_t ws_size,
                              hipStream_t stream) {
    const float* xr = (const float*)d_in[0];
    const float* xi = (const float*)d_in[1];
    const float* cr = (const float*)d_in[2];
    const float* ci = (const float*)d_in[3];
    const int*   ns = (const int*)  d_in[4];

    const int NP  = in_sizes[2] / L_TAPS;   // N*P = 8192
    const int SMK = in_sizes[0] / NP;       // 1120
    (void)d_ws; (void)ws_size; (void)out_size; (void)n_in;

    channel_fused<<<NP, BLOCK, 0, stream>>>(xr, xi, cr, ci, ns,
                                            (float*)d_out, NP, SMK);
}

// Round 7
// 28.277 us; speedup vs baseline: 1.6487x; 1.6487x over previous
//
#include <hip/hip_runtime.h>
#include <math.h>

#define L_TAPS 16
#define M_FFT  64
#define SMAX   128    // max supported S (= Ns+2); bench uses S=14

typedef float v4f __attribute__((ext_vector_type(4)));

__global__ __launch_bounds__(256) void channel_fused(
    const float* __restrict__ xr, const float* __restrict__ xi,
    const float* __restrict__ cr, const float* __restrict__ ci,
    const int*   __restrict__ ns_ptr,
    float* __restrict__ out,          // [NP*SMK] real(out), then [NP*64] real(H_t)
    int NP, int SMK)
{
    __shared__ float  s_cr[L_TAPS], s_ci[L_TAPS];
    __shared__ float2 s_w[SMAX];

    const int np  = blockIdx.x;
    const int tid = threadIdx.x;
    const int S   = ns_ptr[0] + 2;    // N_PILOT = 2
    const int MK  = SMK / S;
    const float two_pi = 6.2831853071795864f;

    // ---- stage cof into LDS (16 lanes) ----
    if (tid < L_TAPS) {
        s_cr[tid] = cr[(size_t)np * L_TAPS + tid];
        s_ci[tid] = ci[(size_t)np * L_TAPS + tid];
    }
    __syncthreads();

    // ---- weights on lanes < S (wave 0): w_s = sum_l cof_l * e^{i*dop_l*t_s} ----
    if (tid < S && S <= SMAX) {
        const float t = (float)tid * (0.0005f / 14.0f);   // reference hard-codes /14
        float wr = 0.f, wi = 0.f;
        #pragma unroll
        for (int l = 0; l < L_TAPS; ++l) {
            float dop = two_pi * 1000.0f                  // fd = V/c*fc = 1000 Hz
                      * __cosf((float)l * (two_pi / (float)(L_TAPS - 1)));
            float sp, cp;
            __sincosf(dop * t, &sp, &cp);
            wr += s_cr[l] * cp - s_ci[l] * sp;
            wi += s_cr[l] * sp + s_ci[l] * cp;
        }
        s_w[tid] = make_float2(wr, wi);
    }

    // ---- H_t on lanes 64..127 (wave 1): Re only ----
    if (tid >= 64 && tid < 64 + M_FFT) {
        const int m = tid - 64;
        float hr = 0.f;
        #pragma unroll
        for (int l = 0; l < L_TAPS; ++l) {
            float sp, cp;
            __sincosf((float)((m * l) & (M_FFT - 1)) * (two_pi / (float)M_FFT),
                      &sp, &cp);
            hr += s_cr[l] * cp + s_ci[l] * sp;   // Re(cof * e^{-i\theta})
        }
        out[(size_t)NP * SMK + (size_t)np * M_FFT + m] = hr;
    }
    __syncthreads();   // s_w ready

    // ---- streaming: out[i] = Re(x[i] * w[i/MK]) ----
    if (S <= SMAX && (MK & 3) == 0 && (SMK & 3) == 0 && (SMK >> 2) <= 512) {
        // fast path: nvec <= 512 -> exactly two predicated shots, all loads
        // issued back-to-back (4 loads in flight/thread, no loop-carried wait)
        const int nvec = SMK >> 2;                 // 280 in bench
        const unsigned mkq = (unsigned)(MK >> 2);
        const size_t gb = (size_t)np * nvec;
        const v4f* xr4 = (const v4f*)xr + gb;
        const v4f* xi4 = (const v4f*)xi + gb;
        v4f*       o4  = (v4f*)out + gb;
        const int i0 = tid, i1 = tid + 256;
        const bool p1 = i1 < nvec;                 // 24 lanes in bench
        v4f a0, b0, a1, b1;
        a0 = xr4[i0];
        b0 = xi4[i0];
        if (p1) { a1 = xr4[i1]; b1 = xi4[i1]; }
        float2 w0 = s_w[(unsigned)i0 / mkq];
        o4[i0] = a0 * w0.x - b0 * w0.y;
        if (p1) {
            float2 w1 = s_w[(unsigned)i1 / mkq];
            o4[i1] = a1 * w1.x - b1 * w1.y;
        }
    } else if (S <= SMAX) {
        const size_t gb = (size_t)np * SMK;
        for (int i = tid; i < SMK; i += 256) {
            float2 w = s_w[(unsigned)i / (unsigned)MK];
            out[gb + i] = xr[gb + i] * w.x - xi[gb + i] * w.y;
        }
    } else {
        // S > SMAX: recompute weight per element — correctness-only path
        const size_t gb = (size_t)np * SMK;
        for (int i = tid; i < SMK; i += 256) {
            int s = i / MK;
            float t = (float)s * (0.0005f / 14.0f);
            float wr = 0.f, wi = 0.f;
            #pragma unroll
            for (int l = 0; l < L_TAPS; ++l) {
                float dop = two_pi * 1000.0f
                          * __cosf((float)l * (two_pi / (float)(L_TAPS - 1)));
                float sp, cp;
                __sincosf(dop * t, &sp, &cp);
                wr += s_cr[l] * cp - s_ci[l] * sp;
                wi += s_cr[l] * sp + s_ci[l] * cp;
            }
            out[gb + i] = xr[gb + i] * wr - xi[gb + i] * wi;
        }
    }
}

extern "C" void kernel_launch(void* const* d_in, const int* in_sizes, int n_in,
                              void* d_out, int out_size, void* d_ws, size_t ws_size,
                              hipStream_t stream) {
    const float* xr = (const float*)d_in[0];
    const float* xi = (const float*)d_in[1];
    const float* cr = (const float*)d_in[2];
    const float* ci = (const float*)d_in[3];
    const int*   ns = (const int*)  d_in[4];

    const int NP  = in_sizes[2] / L_TAPS;   // N*P = 8192
    const int SMK = in_sizes[0] / NP;       // 1120
    (void)d_ws; (void)ws_size; (void)out_size; (void)n_in;

    channel_fused<<<NP, 256, 0, stream>>>(xr, xi, cr, ci, ns,
                                          (float*)d_out, NP, SMK);
}

// Round 8
// 23.877 us; speedup vs baseline: 1.9525x; 1.1843x over previous
//
#include <hip/hip_runtime.h>
#include <math.h>

#define L_TAPS 16
#define M_FFT  64
#define SMAX   256     // max supported S (= Ns+2); bench uses S=14
#define SMK_MAX 2048   // max supported S*MK; bench uses 1120

__global__ __launch_bounds__(256) void channel_kernel(
    const float* __restrict__ xr, const float* __restrict__ xi,
    const float* __restrict__ cr, const float* __restrict__ ci,
    const int*   __restrict__ ns_ptr,
    float* __restrict__ out,      // see `interleaved` flag for layout
    int NP, int SMK, int interleaved)
{
    __shared__ float  s_cr[L_TAPS], s_ci[L_TAPS];
    __shared__ float2 s_w[SMAX];
    __shared__ unsigned short s_smap[SMK_MAX];

    const int np  = blockIdx.x;
    const int tid = threadIdx.x;
    const int S   = ns_ptr[0] + 2;   // N_PILOT = 2
    const int MK  = SMK / S;

    // ---- stage cof into LDS ----
    if (tid < L_TAPS) {
        s_cr[tid] = cr[(size_t)np * L_TAPS + tid];
        s_ci[tid] = ci[(size_t)np * L_TAPS + tid];
    }
    __syncthreads();

    // ---- s-index lookup map: s = i / MK ----
    for (int i = tid; i < SMK; i += 256) {
        s_smap[i] = (unsigned short)(i / MK);
    }

    // ---- weight[s] = sum_l cof[l] * exp(i * 2*pi*cos(angle_l)*fd * t_s) ----
    if (tid < S && tid < SMAX) {
        const float two_pi = 6.2831853071795864f;
        const float dt     = 0.0005f / 14.0f;          // reference hard-codes /14
        const float fd     = 100.0f / 3.0e8f * 3.0e9f; // = 1000 Hz
        const float t      = tid * dt;
        float wr_ = 0.f, wi_ = 0.f;
        #pragma unroll
        for (int l = 0; l < L_TAPS; ++l) {
            float angle = l * (two_pi / 15.0f);        // linspace(0, 2pi, 16)
            float phase = two_pi * __cosf(angle) * fd * t;
            float sp, cp;
            __sincosf(phase, &sp, &cp);
            wr_ += s_cr[l] * cp - s_ci[l] * sp;
            wi_ += s_cr[l] * sp + s_ci[l] * cp;
        }
        s_w[tid] = make_float2(wr_, wi_);
    }

    // ---- H_t[m] = sum_l cof[l] * exp(-2*pi*i*l*m/64)  (threads 64..127) ----
    if (tid >= 64 && tid < 64 + M_FFT) {
        const int m = tid - 64;
        float hr = 0.f, hi = 0.f;
        #pragma unroll
        for (int l = 0; l < L_TAPS; ++l) {
            int ml = (m * l) & (M_FFT - 1);
            float theta = -(float)ml * (6.2831853071795864f / 64.0f);
            float sp, cp;
            __sincosf(theta, &sp, &cp);
            hr += s_cr[l] * cp - s_ci[l] * sp;
            hi += s_cr[l] * sp + s_ci[l] * cp;
        }
        const size_t hbase = (size_t)NP * SMK;
        if (interleaved) {
            ((float2*)out)[hbase + (size_t)np * M_FFT + m] = make_float2(hr, hi);
        } else {
            out[hbase + (size_t)np * M_FFT + m] = hr;   // real part only
        }
    }
    __syncthreads();

    // ---- streaming: out[i] = Re/Complex of x[i] * weight[s(i)] ----
    const size_t base = (size_t)np * SMK;
    if ((MK & 3) == 0 && (SMK & 3) == 0) {
        // vectorized: float4 never straddles an s boundary (MK % 4 == 0)
        const float4* xr4 = (const float4*)(xr + base);
        const float4* xi4 = (const float4*)(xi + base);
        const int nvec = SMK >> 2;
        for (int i = tid; i < nvec; i += 256) {
            float4 a = xr4[i];
            float4 b = xi4[i];
            float2 w = s_w[s_smap[i << 2]];
            float4 re;
            re.x = a.x * w.x - b.x * w.y;
            re.y = a.y * w.x - b.y * w.y;
            re.z = a.z * w.x - b.z * w.y;
            re.w = a.w * w.x - b.w * w.y;
            if (interleaved) {
                float2* o = ((float2*)out) + base;
                o[(i << 2) + 0] = make_float2(re.x, a.x * w.y + b.x * w.x);
                o[(i << 2) + 1] = make_float2(re.y, a.y * w.y + b.y * w.x);
                o[(i << 2) + 2] = make_float2(re.z, a.z * w.y + b.z * w.x);
                o[(i << 2) + 3] = make_float2(re.w, a.w * w.y + b.w * w.x);
            } else {
                ((float4*)(out + base))[i] = re;
            }
        }
    } else {
        for (int i = tid; i < SMK; i += 256) {
            float xre = xr[base + i];
            float xim = xi[base + i];
            float2 w  = s_w[s_smap[i]];
            if (interleaved) {
                ((float2*)out)[base + i] = make_float2(xre * w.x - xim * w.y,
                                                       xre * w.y + xim * w.x);
            } else {
                out[base + i] = xre * w.x - xim * w.y;
            }
        }
    }
}

extern "C" void kernel_launch(void* const* d_in, const int* in_sizes, int n_in,
                              void* d_out, int out_size, void* d_ws, size_t ws_size,
                              hipStream_t stream) {
    const float* xr = (const float*)d_in[0];
    const float* xi = (const float*)d_in[1];
    const float* cr = (const float*)d_in[2];
    const float* ci = (const float*)d_in[3];
    const int*   ns = (const int*)  d_in[4];

    const int NP  = in_sizes[2] / L_TAPS;   // N*P = 8192
    const int SMK = in_sizes[0] / NP;       // 1120

    const int elems = NP * SMK + NP * M_FFT;          // logical complex elements
    const int interleaved = (out_size == 2 * elems) ? 1 : 0;

    channel_kernel<<<NP, 256, 0, stream>>>(xr, xi, cr, ci, ns,
                                           (float*)d_out, NP, SMK, interleaved);
}